// Round 7
// baseline (4506.037 us; speedup 1.0000x reference)
//
#include <hip/hip_runtime.h>
#include <stdint.h>

// LSTM: B=256, T=512, D=128, H=512, C=10
// R16 = R14 (proven 2884us) + runtime-VERIFIED XCD-local L2 transport.
// R15 failed without a profile; its two unverified risks (s_getreg syntax,
// liveness gated on assumed sc0 semantics) are both removed:
//  - XCD co-residency is detected by a FUNCTIONAL handshake: each block
//    plain-stores a magic to its own test line; group blocks sc0-poll all 8
//    lines with a BOUNDED spin. This tests the exact {plain store ->
//    vmcnt(0) -> sc0 load} mechanism the hot loop uses. Bound expiry =>
//    vote fail => agent fallback. No hang possible.
//  - Group consensus on mode via the proven agent-scope vote (votes always
//    arrive; AND of 8 votes => group never mixes transports).
// Local mode is R14 with ONLY the scope swapped (flags kept, one variable
// changed): publish = plain volatile 8B store -> vmcnt(0) -> plain flag
// store; consumer polls flag with sc0 load (L1-bypass, L2 read ~300cy vs
// ~1000cy MALL), then sc0-loads its 4 chunks (8x dwordx2, one waitcnt).
// Same-L2 ordering: producer's vmcnt(0) separates data-commit from flag
// issue; consumer's sc0 reads hit the same L2 array => flag>=t implies
// fresh data. Agent fallback = R14 verbatim.
// Narrow poll + 4-slot rotation carried over unchanged (2-hop closure:
// union of producers of waves 8w..8w+7 = all 32 waves => slot (t+1)%4,
// holding h(t-3), is dead before h(t+1) is published into it).

#define T_STEPS 512
#define BATCH   256
#define DIM     128
#define HID     512
#define NGRP    16
#define BT      16
#define RBUF    4
#define MAGIC   0x5EED5EEDu
#define HSHAKE_BOUND 8192

typedef _Float16 half8 __attribute__((ext_vector_type(8)));
typedef _Float16 half4 __attribute__((ext_vector_type(4)));
typedef float    f32x4 __attribute__((ext_vector_type(4)));
typedef unsigned u32x4 __attribute__((ext_vector_type(4)));

#define SLOT_HALFS (BATCH * HID)
#define SLOT_U64   (SLOT_HALFS / 4)
#define FLG_OFF    (RBUF * SLOT_HALFS * 2)        // 1 MiB of h slots
#define TEST_OFF   (FLG_OFF + NGRP * 32 * 128)    // + wave-flag lines
#define VOTE_OFF   (TEST_OFF + 128 * 128)         // + test lines
#define WS_NEEDED  (VOTE_OFF + 128 * 128)         // + vote lines

__device__ __forceinline__ half8 cvt8(f32x4 a, f32x4 b) {
  half8 r;
  r[0]=(_Float16)a[0]; r[1]=(_Float16)a[1]; r[2]=(_Float16)a[2]; r[3]=(_Float16)a[3];
  r[4]=(_Float16)b[0]; r[5]=(_Float16)b[1]; r[6]=(_Float16)b[2]; r[7]=(_Float16)b[3];
  return r;
}
__device__ __forceinline__ half8 load8_cvt(const float* p) {
  const f32x4* q = (const f32x4*)p;
  return cvt8(q[0], q[1]);
}
__device__ __forceinline__ float fsig(float x) {
  return __builtin_amdgcn_rcpf(1.f + __expf(-x));
}
__device__ __forceinline__ float ftanh(float x) {
  return 1.f - 2.f * __builtin_amdgcn_rcpf(1.f + __expf(2.f * x));
}
// sc0 (L1-bypass) dword load; volatile + memory clobber => re-issued each call
__device__ __forceinline__ unsigned ld_sc0_u32(const unsigned* p) {
  unsigned v;
  asm volatile("global_load_dword %0, %1, off sc0\n\ts_waitcnt vmcnt(0)"
               : "=v"(v) : "v"(p) : "memory");
  return v;
}

union h4u { unsigned long long u; half4 h; };
union c16 { unsigned long long u2[2]; u32x4 v; };

__global__ __launch_bounds__(256, 1) void lstm_persistent(
    const float* __restrict__ X,   const float* __restrict__ Wih,
    const float* __restrict__ Whh, const float* __restrict__ bih,
    const float* __restrict__ bhh, const float* __restrict__ Wlin,
    float* __restrict__ out, _Float16* __restrict__ hbuf,
    unsigned* __restrict__ flg, unsigned* __restrict__ test,
    unsigned* __restrict__ vote)
{
  // double-buffered 16KB h-share; u32 idx = kc*256 + q*64 + col*4
  __shared__ unsigned hsh[2][4096];
  __shared__ int s_mode;

  const int tid  = threadIdx.x;
  const int w    = tid >> 6;
  const int lane = tid & 63;
  const int col  = lane & 15;
  const int q    = lane >> 4;
  const int bid  = blockIdx.x;
  const int g    = bid & 15;         // group
  const int blk  = bid >> 4;         // 0..7 within group
  const int J    = blk * 64 + w * 16;
  const int wid  = blk * 4 + w;      // wave id in group, 0..31
  const int b_my = g * BT + col;

  // ---- W fragments into registers (once) ----
  half8 whh[16][4];
  half8 wih[4][4];
  #pragma unroll
  for (int kc = 0; kc < 16; ++kc)
    #pragma unroll
    for (int mt = 0; mt < 4; ++mt) {
      const int row = mt * HID + J + col;
      whh[kc][mt] = load8_cvt(Whh + (size_t)row * HID + kc * 32 + q * 8);
    }
  #pragma unroll
  for (int xc = 0; xc < 4; ++xc)
    #pragma unroll
    for (int mt = 0; mt < 4; ++mt) {
      const int row = mt * HID + J + col;
      wih[xc][mt] = load8_cvt(Wih + (size_t)row * DIM + xc * 32 + q * 8);
    }

  float bias[4][4], c_st[4], hsum[4];
  #pragma unroll
  for (int mt = 0; mt < 4; ++mt)
    #pragma unroll
    for (int r = 0; r < 4; ++r) {
      const int row = mt * HID + J + q * 4 + r;
      bias[mt][r] = bih[row] + bhh[row];
    }
  #pragma unroll
  for (int r = 0; r < 4; ++r) { c_st[r] = 0.f; hsum[r] = 0.f; }

  // ---- handshake: does {plain store -> vmcnt(0) -> sc0 load} propagate
  //      among this group's 8 blocks? (bounded; hang-impossible) ----
  if (w == 0) {
    if (lane == 0) {
      *(volatile unsigned*)(test + (size_t)bid * 32) = MAGIC;
      asm volatile("s_waitcnt vmcnt(0)" ::: "memory");
    }
    int seen = 1;
    if (lane < 8) {
      const unsigned* tp = test + (size_t)(g + 16 * lane) * 32;
      seen = 0;
      for (int it = 0; it < HSHAKE_BOUND && !seen; ++it)
        seen = (ld_sc0_u32(tp) == MAGIC);
    }
    int ok = __all(seen);
    if (lane == 0)
      __hip_atomic_store(vote + (size_t)bid * 32, ok ? 2u : 1u,
                         __ATOMIC_RELAXED, __HIP_MEMORY_SCOPE_AGENT);
    // gather group votes (always arrive -> no deadlock), consensus = AND
    int vok = 1;
    if (lane < 8) {
      unsigned v;
      do {
        v = __hip_atomic_load(vote + (size_t)(g + 16 * lane) * 32,
                              __ATOMIC_RELAXED, __HIP_MEMORY_SCOPE_AGENT);
      } while (v == 0u);
      vok = (v == 2u);
    }
    if (lane == 0) s_mode = __all(vok);
  }
  __syncthreads();
  const int local = s_mode;

  unsigned* gflg = flg + (size_t)g * 32 * 32;   // 32 wave-flag lines
  const float* Xb = X + (size_t)b_my * T_STEPS * DIM;
  unsigned long long* h64 = (unsigned long long*)hbuf;
  const size_t pub_u64 = ((size_t)b_my * HID + J + q * 4) >> 2;
  const size_t con_u64 = ((size_t)b_my * HID) >> 2;

  // narrow-poll target: wave-ids 8w..8w+7 (producers of this wave's quarter)
  const int  pw   = 8 * w + (lane & 7);
  const bool self = (pw == wid);
  unsigned* pollp = gflg + (size_t)pw * 32;

  // ---- prologue: acc = xp(0); prefetch X(1)->xr1, X(2)->xr0 ----
  f32x4 xr0[8], xr1[8];
  #pragma unroll
  for (int xc = 0; xc < 4; ++xc) {
    const f32x4* p = (const f32x4*)(Xb + xc * 32 + q * 8);
    xr0[2 * xc] = p[0]; xr0[2 * xc + 1] = p[1];
  }
  f32x4 acc[4];
  #pragma unroll
  for (int mt = 0; mt < 4; ++mt) acc[mt] = (f32x4){0.f, 0.f, 0.f, 0.f};
  #pragma unroll
  for (int xc = 0; xc < 4; ++xc) {
    half8 xb = cvt8(xr0[2 * xc], xr0[2 * xc + 1]);
    #pragma unroll
    for (int mt = 0; mt < 4; ++mt)
      acc[mt] = __builtin_amdgcn_mfma_f32_16x16x32_f16(wih[xc][mt], xb, acc[mt], 0, 0, 0);
  }
  #pragma unroll
  for (int xc = 0; xc < 4; ++xc) {
    const f32x4* p1 = (const f32x4*)(Xb + (size_t)1 * DIM + xc * 32 + q * 8);
    const f32x4* p2 = (const f32x4*)(Xb + (size_t)2 * DIM + xc * 32 + q * 8);
    xr1[2 * xc] = p1[0]; xr1[2 * xc + 1] = p1[1];
    xr0[2 * xc] = p2[0]; xr0[2 * xc + 1] = p2[1];
  }

  if (local) {
    // ============ XCD-LOCAL PATH: L2 transport (plain store / sc0 load) ==
    for (int t = 0; t < T_STEPS; ++t) {
      if (t > 0) {
        // narrow flag poll via sc0 (L2 read, ~300cy/iter)
        for (;;) {
          unsigned v = ld_sc0_u32(pollp);
          if (self) v = 0xFFFFFFFFu;
          if (__all((int)(v >= (unsigned)t))) break;
        }
        __builtin_amdgcn_sched_barrier(0);

        // this wave's 4 chunks of h(t) via sc0: 8x dwordx2, ONE waitcnt
        unsigned long long L0,H0,L1,H1,L2x,H2,L3,H3;
        {
          const unsigned long long* base =
              h64 + (size_t)(t & 3) * SLOT_U64 + con_u64 + q * 2;
          const unsigned long long* b0 = base + (size_t)(4 * w + 0) * 8;
          const unsigned long long* b1 = base + (size_t)(4 * w + 1) * 8;
          const unsigned long long* b2 = base + (size_t)(4 * w + 2) * 8;
          const unsigned long long* b3 = base + (size_t)(4 * w + 3) * 8;
          asm volatile(
            "global_load_dwordx2 %0, %8, off sc0\n\t"
            "global_load_dwordx2 %1, %8, off offset:8 sc0\n\t"
            "global_load_dwordx2 %2, %9, off sc0\n\t"
            "global_load_dwordx2 %3, %9, off offset:8 sc0\n\t"
            "global_load_dwordx2 %4, %10, off sc0\n\t"
            "global_load_dwordx2 %5, %10, off offset:8 sc0\n\t"
            "global_load_dwordx2 %6, %11, off sc0\n\t"
            "global_load_dwordx2 %7, %11, off offset:8 sc0\n\t"
            "s_waitcnt vmcnt(0)"
            : "=&v"(L0), "=&v"(H0), "=&v"(L1), "=&v"(H1),
              "=&v"(L2x), "=&v"(H2), "=&v"(L3), "=&v"(H3)
            : "v"(b0), "v"(b1), "v"(b2), "v"(b3)
            : "memory");
        }
        // stage to LDS (swizzled, conflict-free), buffer t&1
        { c16 u; u.u2[0]=L0; u.u2[1]=H0;
          *(u32x4*)(&hsh[t & 1][(4*w+0)*256 + q*64 + col*4]) = u.v; }
        { c16 u; u.u2[0]=L1; u.u2[1]=H1;
          *(u32x4*)(&hsh[t & 1][(4*w+1)*256 + q*64 + col*4]) = u.v; }
        { c16 u; u.u2[0]=L2x; u.u2[1]=H2;
          *(u32x4*)(&hsh[t & 1][(4*w+2)*256 + q*64 + col*4]) = u.v; }
        { c16 u; u.u2[0]=L3; u.u2[1]=H3;
          *(u32x4*)(&hsh[t & 1][(4*w+3)*256 + q*64 + col*4]) = u.v; }
        __syncthreads();

        // full h(t) from LDS -> MFMA
        #pragma unroll
        for (int kc = 0; kc < 16; ++kc) {
          const half8 hbv = *(const half8*)(&hsh[t & 1][kc * 256 + q * 64 + col * 4]);
          #pragma unroll
          for (int mt = 0; mt < 4; ++mt)
            acc[mt] = __builtin_amdgcn_mfma_f32_16x16x32_f16(whh[kc][mt], hbv, acc[mt], 0, 0, 0);
        }
      }

      // gates
      h4u hv;
      #pragma unroll
      for (int r = 0; r < 4; ++r) {
        const float ig = fsig(acc[0][r] + bias[0][r]);
        const float fg = fsig(acc[1][r] + bias[1][r]);
        const float gg = ftanh(acc[2][r] + bias[2][r]);
        const float og = fsig(acc[3][r] + bias[3][r]);
        const float cc = fg * c_st[r] + ig * gg;
        c_st[r] = cc;
        const float h = og * ftanh(cc);
        hsum[r] += h;
        hv.h[r] = (_Float16)h;
      }

      if (t + 1 < T_STEPS) {
        // publish h(t+1): plain volatile 8B store (L1 write-through -> L2)
        *(volatile unsigned long long*)
            (h64 + (size_t)((t + 1) & 3) * SLOT_U64 + pub_u64) = hv.u;
        // drain own stores (L2 ack ~300cy), then plain flag store
        asm volatile("s_waitcnt vmcnt(0)" ::: "memory");
        if (lane == 0)
          *(volatile unsigned*)(gflg + (size_t)wid * 32) = (unsigned)(t + 1);

        // X(t+2) prefetch (after flag: drains never block the release)
        {
          const int tn = (t + 2 < T_STEPS) ? (t + 2) : (T_STEPS - 1);
          const float* xp = Xb + (size_t)tn * DIM + q * 8;
          f32x4* dst = (t & 1) ? xr1 : xr0;
          #pragma unroll
          for (int xc = 0; xc < 4; ++xc) {
            const f32x4* src = (const f32x4*)(xp + xc * 32);
            dst[2 * xc]     = src[0];
            dst[2 * xc + 1] = src[1];
          }
        }
        // xp(t+1) MFMA from buf[(t+1)&1]
        #pragma unroll
        for (int mt = 0; mt < 4; ++mt) acc[mt] = (f32x4){0.f, 0.f, 0.f, 0.f};
        const f32x4* xbuf = ((t + 1) & 1) ? xr1 : xr0;
        #pragma unroll
        for (int xc = 0; xc < 4; ++xc) {
          half8 xb = cvt8(xbuf[2 * xc], xbuf[2 * xc + 1]);
          #pragma unroll
          for (int mt = 0; mt < 4; ++mt)
            acc[mt] = __builtin_amdgcn_mfma_f32_16x16x32_f16(wih[xc][mt], xb, acc[mt], 0, 0, 0);
        }
      }
    }
  } else {
    // ================= AGENT FALLBACK (R14 verbatim) ====================
    for (int t = 0; t < T_STEPS; ++t) {
      if (t > 0) {
        for (;;) {
          unsigned v = __hip_atomic_load(pollp, __ATOMIC_RELAXED,
                                         __HIP_MEMORY_SCOPE_AGENT);
          if (self) v = 0xFFFFFFFFu;
          if (__all((int)(v >= (unsigned)t))) break;
        }
        __builtin_amdgcn_sched_barrier(0);

        unsigned long long lo[4], hi[4];
        {
          const unsigned long long* base =
              h64 + (size_t)(t & 3) * SLOT_U64 + con_u64;
          #pragma unroll
          for (int i = 0; i < 4; ++i) {
            const int kc = w * 4 + i;
            lo[i] = __hip_atomic_load(base + kc * 8 + q * 2,     __ATOMIC_RELAXED, __HIP_MEMORY_SCOPE_AGENT);
            hi[i] = __hip_atomic_load(base + kc * 8 + q * 2 + 1, __ATOMIC_RELAXED, __HIP_MEMORY_SCOPE_AGENT);
          }
        }
        #pragma unroll
        for (int i = 0; i < 4; ++i) {
          const int kc = w * 4 + i;
          c16 u; u.u2[0] = lo[i]; u.u2[1] = hi[i];
          *(u32x4*)(&hsh[t & 1][kc * 256 + q * 64 + col * 4]) = u.v;
        }
        __syncthreads();

        #pragma unroll
        for (int kc = 0; kc < 16; ++kc) {
          const half8 hbv = *(const half8*)(&hsh[t & 1][kc * 256 + q * 64 + col * 4]);
          #pragma unroll
          for (int mt = 0; mt < 4; ++mt)
            acc[mt] = __builtin_amdgcn_mfma_f32_16x16x32_f16(whh[kc][mt], hbv, acc[mt], 0, 0, 0);
        }
      }

      h4u hv;
      #pragma unroll
      for (int r = 0; r < 4; ++r) {
        const float ig = fsig(acc[0][r] + bias[0][r]);
        const float fg = fsig(acc[1][r] + bias[1][r]);
        const float gg = ftanh(acc[2][r] + bias[2][r]);
        const float og = fsig(acc[3][r] + bias[3][r]);
        const float cc = fg * c_st[r] + ig * gg;
        c_st[r] = cc;
        const float h = og * ftanh(cc);
        hsum[r] += h;
        hv.h[r] = (_Float16)h;
      }

      if (t + 1 < T_STEPS) {
        __hip_atomic_store(h64 + (size_t)((t + 1) & 3) * SLOT_U64 + pub_u64,
                           hv.u, __ATOMIC_RELAXED, __HIP_MEMORY_SCOPE_AGENT);
        asm volatile("s_waitcnt vmcnt(0)" ::: "memory");
        if (lane == 0)
          __hip_atomic_store(gflg + (size_t)wid * 32, (unsigned)(t + 1),
                             __ATOMIC_RELAXED, __HIP_MEMORY_SCOPE_AGENT);
        {
          const int tn = (t + 2 < T_STEPS) ? (t + 2) : (T_STEPS - 1);
          const float* xp = Xb + (size_t)tn * DIM + q * 8;
          f32x4* dst = (t & 1) ? xr1 : xr0;
          #pragma unroll
          for (int xc = 0; xc < 4; ++xc) {
            const f32x4* src = (const f32x4*)(xp + xc * 32);
            dst[2 * xc]     = src[0];
            dst[2 * xc + 1] = src[1];
          }
        }
        #pragma unroll
        for (int mt = 0; mt < 4; ++mt) acc[mt] = (f32x4){0.f, 0.f, 0.f, 0.f};
        const f32x4* xbuf = ((t + 1) & 1) ? xr1 : xr0;
        #pragma unroll
        for (int xc = 0; xc < 4; ++xc) {
          half8 xb = cvt8(xbuf[2 * xc], xbuf[2 * xc + 1]);
          #pragma unroll
          for (int mt = 0; mt < 4; ++mt)
            acc[mt] = __builtin_amdgcn_mfma_f32_16x16x32_f16(wih[xc][mt], xb, acc[mt], 0, 0, 0);
        }
      }
    }
  }

  // epilogue: logits += mean_h * W_lin^T (bias pre-set by init kernel)
  const float inv = 1.0f / (float)T_STEPS;
  float m[4];
  #pragma unroll
  for (int r = 0; r < 4; ++r) m[r] = hsum[r] * inv;
  #pragma unroll
  for (int cls = 0; cls < 10; ++cls) {
    f32x4 wl = *(const f32x4*)(Wlin + (size_t)cls * HID + J + q * 4);
    float p = m[0] * wl[0] + m[1] * wl[1] + m[2] * wl[2] + m[3] * wl[3];
    p += __shfl_xor(p, 16, 64);
    p += __shfl_xor(p, 32, 64);
    if (q == 0) atomicAdd(out + b_my * 10 + cls, p);
  }
}

__global__ void init_out(const float* __restrict__ blin, float* __restrict__ out) {
  const int i = blockIdx.x * blockDim.x + threadIdx.x;
  if (i < BATCH * 10) out[i] = blin[i % 10];
}

extern "C" void kernel_launch(void* const* d_in, const int* in_sizes, int n_in,
                              void* d_out, int out_size, void* d_ws, size_t ws_size,
                              hipStream_t stream) {
  const float* X    = (const float*)d_in[0];
  const float* Wih  = (const float*)d_in[1];
  const float* Whh  = (const float*)d_in[2];
  const float* bih  = (const float*)d_in[3];
  const float* bhh  = (const float*)d_in[4];
  const float* Wlin = (const float*)d_in[5];
  const float* blin = (const float*)d_in[6];
  float* out = (float*)d_out;

  if (ws_size < (size_t)WS_NEEDED) return;

  _Float16* hbuf  = (_Float16*)d_ws;
  unsigned* flg   = (unsigned*)((char*)d_ws + FLG_OFF);
  unsigned* test  = (unsigned*)((char*)d_ws + TEST_OFF);
  unsigned* vote  = (unsigned*)((char*)d_ws + VOTE_OFF);

  // flags + test + vote zeroed each launch; h slots are flag-gated
  hipMemsetAsync((char*)d_ws + FLG_OFF, 0, WS_NEEDED - FLG_OFF, stream);
  init_out<<<10, 256, 0, stream>>>(blin, out);
  lstm_persistent<<<128, 256, 0, stream>>>(X, Wih, Whh, bih, bhh, Wlin, out,
                                           hbuf, flg, test, vote);
}